// Round 12
// baseline (2013.671 us; speedup 1.0000x reference)
//
#include <hip/hip_runtime.h>

// ---------------------------------------------------------------------------
// GCN 3-layer forward as ONE persistent cooperative kernel (11 grid barriers)
// + tiny barrier-init kernel. Rationale: R11 accounting showed ~100us (20%)
// of wall time is inter-dispatch overhead across 12 launches.
// Coherence: hbf/bufA are rewritten across phases -> their cross-phase reads
// are volatile (sc0, bypass L1). All other buffers are write-once-then-read.
// d_ws layout (<=102.4 MB; 119.2 MB proven safe):
//   [0)       packed N u64 | [1MB) dis | [1536K) flag
//   [1536K+4K) bsums | [1536K+8K) barrier leaf[1024]+root+gen
//   [1600K)   row_start | [2560K) csr E int2 | [15872K) Wt1,Wt2,Wt3
//   [16MB)    bufA bf16 xw | [42MB) hbf bf16 x/h | [96MB) eseq E ints
// ---------------------------------------------------------------------------

typedef __attribute__((ext_vector_type(8))) short bf16x8;
typedef __attribute__((ext_vector_type(4))) float f32x4;

__device__ inline unsigned short f2bf(float f) {   // RNE f32 -> bf16
  unsigned int u = __float_as_uint(f);
  u += 0x7fffu + ((u >> 16) & 1u);
  return (unsigned short)(u >> 16);
}
__device__ inline float bflo(unsigned int u) { return __uint_as_float(u << 16); }
__device__ inline float bfhi(unsigned int u) { return __uint_as_float(u & 0xffff0000u); }

struct GcnP {
  const int* ei; const float* ew;
  const float* W1; const float* b1; const float* W2; const float* b2;
  const float* W3; const float* b3; const float* x;
  float* out;
  unsigned long long* packed; float* dis; int* flag; int* bsums;
  int* leaf; int* root; int* gen;
  int* row_start; int2* csr;
  unsigned short* Wt1; unsigned short* Wt2; unsigned short* Wt3;
  unsigned short* bufA; unsigned short* hbf; int* eseq;
  int N, E, B, gGemm, gGather;
  long long n4;
};

// Hierarchical grid barrier: 64 leaf counters (padded lines) -> root -> gen.
// Requires gridDim.x to be a multiple of 64; all blocks resident (coop launch).
__device__ inline void gbar(int* leaf, int* root, volatile int* gen) {
  __threadfence();
  __syncthreads();
  if (threadIdx.x == 0) {
    const int g = *gen;
    const int li = blockIdx.x & 63;
    const int expct = (int)(gridDim.x >> 6);
    if (atomicAdd(&leaf[li << 4], 1) == expct - 1) {
      atomicExch(&leaf[li << 4], 0);
      if (atomicAdd(root, 1) == 63) {
        atomicExch(root, 0);
        __threadfence();
        atomicAdd((int*)gen, 1);
      }
    }
    while (*gen == g) __builtin_amdgcn_s_sleep(4);
    __threadfence();
  }
  __syncthreads();
}

template <int M>
__device__ inline void gemm_tile(int b, const unsigned short* A,
                                 const unsigned short* Bt, unsigned short* C, int N) {
  const int tid = threadIdx.x;
  const int lane = tid & 63;
  const int m = lane & 15;
  const int q = lane >> 4;
  const int row0 = (b << 6) + ((tid >> 6) << 4);
  const bool rowok = (row0 + m) < N;
  bf16x8 a[4];
  const volatile unsigned int* a32 =
      (const volatile unsigned int*)(A + (long long)(row0 + m) * 128) + q * 4;
#pragma unroll
  for (int kt = 0; kt < 4; ++kt) {
    union { unsigned int u[4]; bf16x8 v; } cv;
    if (rowok) {
      cv.u[0] = a32[kt * 16 + 0]; cv.u[1] = a32[kt * 16 + 1];
      cv.u[2] = a32[kt * 16 + 2]; cv.u[3] = a32[kt * 16 + 3];
    } else {
      cv.u[0] = cv.u[1] = cv.u[2] = cv.u[3] = 0u;
    }
    a[kt] = cv.v;
  }
#pragma unroll
  for (int ct = 0; ct < M / 16; ++ct) {
    f32x4 acc = {0.f, 0.f, 0.f, 0.f};
    const unsigned short* brow = Bt + (ct * 16 + m) * 128 + q * 8;
#pragma unroll
    for (int kt = 0; kt < 4; ++kt) {
      const bf16x8 bb = *(const bf16x8*)(brow + kt * 32);
      acc = __builtin_amdgcn_mfma_f32_16x16x32_bf16(a[kt], bb, acc, 0, 0, 0);
    }
#pragma unroll
    for (int r = 0; r < 4; ++r) {
      const int row = row0 + q * 4 + r;
      if (row < N) C[(long long)row * M + ct * 16 + m] = f2bf(acc[r]);
    }
  }
}

template <int M, bool RELU, bool OUTBF>
__device__ inline void gather_node(int node, const int2* csr, const int* row_start,
                                   const unsigned short* xw, const float* dis,
                                   const float* bias, void* outp, int N) {
  const int lane = threadIdx.x & 63;
  const int beg = __builtin_amdgcn_readfirstlane(row_start[node]);
  const int end = __builtin_amdgcn_readfirstlane(row_start[node + 1]);
  if (M == 128) {
    const int c = lane << 1;
    float2 a0 = make_float2(0.f, 0.f), a1 = a0, a2 = a0, a3 = a0;
    int e = beg;
    for (; e + 7 < end; e += 8) {
      int2 p[8];
      unsigned int u[8];
#pragma unroll
      for (int j = 0; j < 8; ++j) p[j] = csr[e + j];
#pragma unroll
      for (int j = 0; j < 8; ++j)
        u[j] = *(const volatile unsigned int*)(xw + (long long)p[j].x * 128 + c);
#pragma unroll
      for (int j = 0; j < 8; ++j) {
        const float nm = __int_as_float(p[j].y);
        float2& ac = (j & 4) ? ((j & 2) ? a3 : a2) : ((j & 2) ? a1 : a0);
        ac.x = fmaf(nm, bflo(u[j]), ac.x);
        ac.y = fmaf(nm, bfhi(u[j]), ac.y);
      }
    }
    for (; e + 1 < end; e += 2) {
      const int2 p0 = csr[e], p1 = csr[e + 1];
      const unsigned int u0 = *(const volatile unsigned int*)(xw + (long long)p0.x * 128 + c);
      const unsigned int u1 = *(const volatile unsigned int*)(xw + (long long)p1.x * 128 + c);
      const float n0 = __int_as_float(p0.y), n1 = __int_as_float(p1.y);
      a0.x = fmaf(n0, bflo(u0), a0.x);
      a0.y = fmaf(n0, bfhi(u0), a0.y);
      a1.x = fmaf(n1, bflo(u1), a1.x);
      a1.y = fmaf(n1, bfhi(u1), a1.y);
    }
    if (e < end) {
      const int2 p = csr[e];
      const float nm = __int_as_float(p.y);
      const unsigned int u = *(const volatile unsigned int*)(xw + (long long)p.x * 128 + c);
      a2.x = fmaf(nm, bflo(u), a2.x);
      a2.y = fmaf(nm, bfhi(u), a2.y);
    }
    float2 acc;
    acc.x = (a0.x + a1.x) + (a2.x + a3.x);
    acc.y = (a0.y + a1.y) + (a2.y + a3.y);
    const float di = dis[node];
    const float dsq = di * di;
    const unsigned int su = *(const volatile unsigned int*)(xw + (long long)node * 128 + c);
    const float2 bv = *(const float2*)(bias + c);
    acc.x = fmaf(dsq, bflo(su), acc.x) + bv.x;
    acc.y = fmaf(dsq, bfhi(su), acc.y) + bv.y;
    if (RELU) { acc.x = fmaxf(acc.x, 0.f); acc.y = fmaxf(acc.y, 0.f); }
    if (OUTBF) {
      const unsigned int pk =
          (unsigned int)f2bf(acc.x) | ((unsigned int)f2bf(acc.y) << 16);
      ((unsigned int*)outp)[(long long)node * 64 + lane] = pk;
    } else {
      *(float2*)((float*)outp + (long long)node * 128 + c) = acc;
    }
  } else {
    float a0 = 0.f, a1 = 0.f, a2 = 0.f, a3 = 0.f;
    int e = beg;
    for (; e + 7 < end; e += 8) {
      int2 p[8];
      unsigned int v[8];
#pragma unroll
      for (int j = 0; j < 8; ++j) p[j] = csr[e + j];
#pragma unroll
      for (int j = 0; j < 8; ++j)
        v[j] = *(const volatile unsigned short*)(xw + (long long)p[j].x * 64 + lane);
#pragma unroll
      for (int j = 0; j < 8; ++j) {
        float& ac = (j & 4) ? ((j & 2) ? a3 : a2) : ((j & 2) ? a1 : a0);
        ac = fmaf(__int_as_float(p[j].y), bflo(v[j]), ac);
      }
    }
    for (; e < end; ++e) {
      const int2 p = csr[e];
      const unsigned int v = *(const volatile unsigned short*)(xw + (long long)p.x * 64 + lane);
      a0 = fmaf(__int_as_float(p.y), bflo(v), a0);
    }
    float acc = (a0 + a1) + (a2 + a3);
    const float di = dis[node];
    const unsigned int sv = *(const volatile unsigned short*)(xw + (long long)node * 64 + lane);
    float r = fmaf(di * di, bflo(sv), acc) + bias[lane];
    if (RELU) r = fmaxf(r, 0.f);
    ((float*)outp)[(long long)node * 64 + lane] = r;
  }
}

__global__ void init_bar(int* leaf) {   // zero leaf[1024] + root + gen
  const int i = threadIdx.x;
  for (int j = i; j < 1026; j += 256) leaf[j] = 0;
}

__global__ __launch_bounds__(256, 6)
void gcn_all(GcnP p) {
  __shared__ int red[256];
  __shared__ int misc;
  const int tid = threadIdx.x;
  const int nb = gridDim.x;
  const int bid = blockIdx.x;

  // ---- P0: zero packed; detect int64; W->bf16^T; x->bf16 ----
  {
    int* pz = (int*)p.packed;
    const int nz = 2 * p.N;
    for (int i = bid * 256 + tid; i < nz; i += nb * 256) pz[i] = 0;
    if (bid == 0) {
      if (tid == 0) misc = 0;
      __syncthreads();
      int acc = 0;
#pragma unroll
      for (int it = 0; it < 8; ++it) acc |= p.ei[2 * (tid + (it << 8)) + 1];
      if (acc != 0) atomicOr(&misc, 1);
      __syncthreads();
      if (tid == 0) p.flag[0] = (misc == 0) ? 1 : 0;
    }
    if (bid < 160) {
      const int idx = bid * 256 + tid;
      if (idx < 16384) {
        const int m = idx >> 7, k = idx & 127;
        p.Wt1[idx] = f2bf(p.W1[k * 128 + m]);
      } else if (idx < 32768) {
        const int l = idx - 16384;
        const int m = l >> 7, k = l & 127;
        p.Wt2[l] = f2bf(p.W2[k * 128 + m]);
      } else {
        const int l = idx - 32768;
        const int m = l >> 7, k = l & 127;
        p.Wt3[l] = f2bf(p.W3[k * 64 + m]);
      }
    } else {
      for (long long i = (long long)(bid - 160) * 256 + tid; i < p.n4;
           i += (long long)(nb - 160) * 256) {
        const float4 v = ((const float4*)p.x)[i];
        ushort4 o;
        o.x = f2bf(v.x); o.y = f2bf(v.y); o.z = f2bf(v.z); o.w = f2bf(v.w);
        ((ushort4*)p.hbf)[i] = o;
      }
    }
  }
  gbar(p.leaf, p.root, p.gen);

  // ---- P1: count+deg packed atomic ----
  {
    const int use64 = p.flag[0];
    for (int e = bid * 256 + tid; e < p.E; e += nb * 256) {
      const int d = use64 ? p.ei[2 * (p.E + e)] : p.ei[p.E + e];
      const unsigned int fx = (unsigned int)(p.ew[e] * 16777216.0f);
      const unsigned long long old =
          atomicAdd(&p.packed[d], (1ULL << 32) | (unsigned long long)fx);
      p.eseq[e] = (int)(old >> 32);
    }
  }
  gbar(p.leaf, p.root, p.gen);

  // ---- P2: per-chunk reduction -> bsums ----
  for (int c = bid; c < p.B; c += nb) {
    const int base = c * 1024 + tid * 4;
    int s = 0;
#pragma unroll
    for (int j = 0; j < 4; ++j)
      if (base + j < p.N) s += (int)(p.packed[base + j] >> 32);
    red[tid] = s;
    __syncthreads();
    for (int off = 128; off > 0; off >>= 1) {
      if (tid < off) red[tid] += red[tid + off];
      __syncthreads();
    }
    if (tid == 0) p.bsums[c] = red[0];
    __syncthreads();
  }
  gbar(p.leaf, p.root, p.gen);

  // ---- P3: block 0 exclusive-scans bsums ----
  if (bid == 0) {
    int v[4];
#pragma unroll
    for (int j = 0; j < 4; ++j) {
      const int idx = tid * 4 + j;
      v[j] = (idx < p.B) ? p.bsums[idx] : 0;
    }
    const int tot = v[0] + v[1] + v[2] + v[3];
    red[tid] = tot;
    __syncthreads();
    for (int off = 1; off < 256; off <<= 1) {
      const int add = (tid >= off) ? red[tid - off] : 0;
      __syncthreads();
      red[tid] += add;
      __syncthreads();
    }
    int run = red[tid] - tot;
#pragma unroll
    for (int j = 0; j < 4; ++j) {
      const int idx = tid * 4 + j;
      if (idx < p.B) { p.bsums[idx] = run; run += v[j]; }
    }
    if (tid == 255) p.row_start[p.N] = red[255];
  }
  gbar(p.leaf, p.root, p.gen);

  // ---- P4: row_start + dis ----
  for (int c = bid; c < p.B; c += nb) {
    const int base = c * 1024 + tid * 4;
    unsigned long long pk[4];
    int v[4];
#pragma unroll
    for (int j = 0; j < 4; ++j) {
      pk[j] = (base + j < p.N) ? p.packed[base + j] : 0ULL;
      v[j] = (int)(pk[j] >> 32);
    }
    const int tot = v[0] + v[1] + v[2] + v[3];
    red[tid] = tot;
    __syncthreads();
    for (int off = 1; off < 256; off <<= 1) {
      const int add = (tid >= off) ? red[tid - off] : 0;
      __syncthreads();
      red[tid] += add;
      __syncthreads();
    }
    int run = *(volatile int*)&p.bsums[c] + red[tid] - tot;
#pragma unroll
    for (int j = 0; j < 4; ++j) {
      const int idx = base + j;
      if (idx < p.N) {
        p.row_start[idx] = run;
        run += v[j];
        const float deg = (float)(unsigned int)pk[j] * (1.0f / 16777216.0f);
        p.dis[idx] = rsqrtf(deg + 1.0f);
      }
    }
    __syncthreads();
  }
  gbar(p.leaf, p.root, p.gen);

  // ---- P5: fill CSR ----
  {
    const int use64 = p.flag[0];
    for (int e = bid * 256 + tid; e < p.E; e += nb * 256) {
      const int s = use64 ? p.ei[2 * e] : p.ei[e];
      const int d = use64 ? p.ei[2 * (p.E + e)] : p.ei[p.E + e];
      const float nm = p.dis[s] * p.ew[e] * p.dis[d];
      p.csr[p.row_start[d] + p.eseq[e]] = make_int2(s, __float_as_int(nm));
    }
  }
  gbar(p.leaf, p.root, p.gen);

  // ---- layers ----
  for (int b = bid; b < p.gGemm; b += nb) gemm_tile<128>(b, p.hbf, p.Wt1, p.bufA, p.N);
  gbar(p.leaf, p.root, p.gen);
  for (int g = bid; g < p.gGather; g += nb) {
    const int node = (g << 2) + (tid >> 6);
    if (node < p.N)
      gather_node<128, true, true>(node, p.csr, p.row_start, p.bufA, p.dis, p.b1, p.hbf, p.N);
  }
  gbar(p.leaf, p.root, p.gen);
  for (int b = bid; b < p.gGemm; b += nb) gemm_tile<128>(b, p.hbf, p.Wt2, p.bufA, p.N);
  gbar(p.leaf, p.root, p.gen);
  for (int g = bid; g < p.gGather; g += nb) {
    const int node = (g << 2) + (tid >> 6);
    if (node < p.N)
      gather_node<128, true, true>(node, p.csr, p.row_start, p.bufA, p.dis, p.b2, p.hbf, p.N);
  }
  gbar(p.leaf, p.root, p.gen);
  for (int b = bid; b < p.gGemm; b += nb) gemm_tile<64>(b, p.hbf, p.Wt3, p.bufA, p.N);
  gbar(p.leaf, p.root, p.gen);
  for (int g = bid; g < p.gGather; g += nb) {
    const int node = (g << 2) + (tid >> 6);
    if (node < p.N)
      gather_node<64, false, false>(node, p.csr, p.row_start, p.bufA, p.dis, p.b3, p.out, p.N);
  }
}

extern "C" void kernel_launch(void* const* d_in, const int* in_sizes, int n_in,
                              void* d_out, int out_size, void* d_ws, size_t ws_size,
                              hipStream_t stream) {
  const int IN = 128;
  const int N = in_sizes[0] / IN;   // 100000
  const int E = in_sizes[2];        // 1600000

  char* ws = (char*)d_ws;
  GcnP p;
  p.ei = (const int*)d_in[1];
  p.ew = (const float*)d_in[2];
  p.W1 = (const float*)d_in[3]; p.b1 = (const float*)d_in[4];
  p.W2 = (const float*)d_in[5]; p.b2 = (const float*)d_in[6];
  p.W3 = (const float*)d_in[7]; p.b3 = (const float*)d_in[8];
  p.x  = (const float*)d_in[0];
  p.out = (float*)d_out;
  p.packed = (unsigned long long*)(ws);
  p.dis = (float*)(ws + (1u << 20));
  p.flag = (int*)(ws + (1536u << 10));
  p.bsums = (int*)(ws + (1536u << 10) + 4096);
  p.leaf = (int*)(ws + (1536u << 10) + 8192);
  p.root = p.leaf + 1024;
  p.gen  = p.root + 1;
  p.row_start = (int*)(ws + (1600u << 10));
  p.csr = (int2*)(ws + (2560u << 10));
  p.Wt1 = (unsigned short*)(ws + (15872u << 10));
  p.Wt2 = (unsigned short*)(ws + (15872u << 10) + (128u << 10));
  p.Wt3 = (unsigned short*)(ws + (15872u << 10) + (256u << 10));
  p.bufA = (unsigned short*)(ws + (16u << 20));
  p.hbf  = (unsigned short*)(ws + (42u << 20));
  p.eseq = (int*)(ws + (96u << 20));
  p.N = N; p.E = E;
  p.B = (N + 1023) / 1024;
  p.gGemm = (N + 63) / 64;
  p.gGather = (N + 3) / 4;
  p.n4 = (long long)N * 32;

  // Grid = full co-resident capacity (cooperative launch validates residency).
  int dev = 0;
  hipGetDevice(&dev);
  int numCU = 256;
  hipDeviceGetAttribute(&numCU, hipDeviceAttributeMultiprocessorCount, dev);
  int bpc = 0;
  if (hipOccupancyMaxActiveBlocksPerMultiprocessor(&bpc, gcn_all, 256, 0) != hipSuccess ||
      bpc < 1)
    bpc = 1;
  int grid = bpc * numCU;
  if (grid > 2048) grid = 2048;
  grid &= ~63;               // barrier assumes multiple of 64
  if (grid < 64) grid = 64;

  hipLaunchKernelGGL(init_bar, dim3(1), dim3(256), 0, stream, p.leaf);
  void* kargs[] = {(void*)&p};
  hipLaunchCooperativeKernel((void*)gcn_all, dim3(grid), dim3(256), kargs, 0, stream);
}